// Round 1
// 155.603 us; speedup vs baseline: 1.0071x; 1.0071x over previous
//
#include <hip/hip_runtime.h>
#include <hip/hip_cooperative_groups.h>
#include <float.h>
#include <math.h>

// Problem constants
#define BATCH   8192
#define NCH     45
#define SEQL    21
#define NEXP    22
#define NUN     23           // NCH - NEXP
#define ROWLEN  945          // NCH*SEQL
#define GOFF    7741440      // BATCH*ROWLEN, start of A_flat in d_out
#define GRID    1024         // fused kernel: 8 batches per block
#define K3_BLOCKS 2048       // fallback path
#define LOG2E   1.4426950408889634f

namespace cg = cooperative_groups;

__device__ __forceinline__ float fast_tanh(float v) {
    const float t = __expf(2.f * v);
    return (t - 1.f) / (t + 1.f);
}

// =====================================================================
// Fused cooperative kernel: gate (A) -> grid.sync -> reduce (B) ->
// grid.sync -> top-k + attention (C).  x staged to LDS ONCE for both
// phase A and phase C (same 8 batches per block).
// =====================================================================
__global__ __launch_bounds__(256, 4) void kfused(
    const float* __restrict__ x,
    const float* __restrict__ gc_w, const float* __restrict__ gc_b,
    const float* __restrict__ w1,   const float* __restrict__ b1,
    const float* __restrict__ w2,   const float* __restrict__ b2,
    const float* __restrict__ wq,   const float* __restrict__ bq,
    const float* __restrict__ wk,   const float* __restrict__ bk,
    const float* __restrict__ wv,   const float* __restrict__ bv,
    const float* __restrict__ wo,   const float* __restrict__ bo,
    float* __restrict__ partialsT,  float* __restrict__ mg,
    float* __restrict__ escal,      float* __restrict__ out)
{
    __shared__ float xsh[8 * ROWLEN];      // 30240 B, lives through phase C
    __shared__ float buf45a[4][45], buf45b[4][45];
    __shared__ float buf25a[4][25], buf25b[4][25];
    __shared__ float part[4][45];
    __shared__ float gat[8][45];           // gates of this block's 8 batches
    __shared__ float smg[64];
    __shared__ float sA[NEXP], sC[NEXP], sP[NEXP], sQ[NEXP];
    __shared__ int   ssel[NEXP], sunsel[NUN];
    __shared__ float wsum[4];

    const int tid  = threadIdx.x;
    const int w    = tid >> 6;
    const int lane = tid & 63;
    const int b_base = blockIdx.x * 8;

    // ---------------- Phase A: gating ----------------
    {
        const float4* x4 = (const float4*)(x + (size_t)b_base * ROWLEN);
        float4* xsh4 = (float4*)xsh;
        for (int q = tid; q < 1890; q += 256) xsh4[q] = x4[q];
    }
    __syncthreads();

    float accg = 0.f;
    for (int iter = 0; iter < 2; ++iter) {
        const int bb = w * 2 + iter;        // local row 0..7
        float g = 0.f;
        if (lane < NCH) {
            float xr[SEQL];
            const float* xp = &xsh[bb * ROWLEN + lane * SEQL];
            #pragma unroll
            for (int l = 0; l < SEQL; ++l) xr[l] = xp[l];
            float mx = -FLT_MAX, av = 0.f;
            for (int o = 0; o < SEQL; ++o) {
                float t = gc_b[o];
                #pragma unroll
                for (int l = 0; l < SEQL; ++l) t = fmaf(gc_w[o * SEQL + l], xr[l], t);
                mx = fmaxf(mx, t);
                av += t;
            }
            av *= (1.f / 21.f);
            buf45a[w][lane] = mx;
            buf45b[w][lane] = av;
        }
        __syncthreads();
        if (lane < 25) {
            float tm = b1[lane], ta = b1[lane];
            for (int i = 0; i < NCH; ++i) {
                const float wv_ = w1[lane * NCH + i];
                tm = fmaf(wv_, buf45a[w][i], tm);
                ta = fmaf(wv_, buf45b[w][i], ta);
            }
            buf25a[w][lane] = fast_tanh(tm);
            buf25b[w][lane] = fast_tanh(ta);
        }
        __syncthreads();
        if (lane < NCH) {
            float tm = b2[lane], ta = b2[lane];
            for (int j = 0; j < 25; ++j) {
                const float wv_ = w2[lane * 25 + j];
                tm = fmaf(wv_, buf25a[w][j], tm);
                ta = fmaf(wv_, buf25b[w][j], ta);
            }
            g = __expf(fast_tanh(tm) + fast_tanh(ta));
            buf45a[w][lane] = g;
        }
        __syncthreads();
        if (lane < NCH) {
            float s = 0.f;
            for (int i = 0; i < NCH; ++i) s += buf45a[w][i];
            const float gt = g / s;
            gat[bb][lane] = gt;             // keep gate in LDS (no global round-trip)
            accg += gt;
        }
        __syncthreads();
    }

    if (lane < NCH) part[w][lane] = accg;
    __syncthreads();
    if (tid < NCH)
        partialsT[tid * GRID + blockIdx.x] =
            part[0][tid] + part[1][tid] + part[2][tid] + part[3][tid];

    cg::this_grid().sync();

    // ---------------- Phase B: blocks 0..44 reduce, block 45 expert scalars ---
    if (blockIdx.x < NCH) {
        const float4 v = ((const float4*)(partialsT + blockIdx.x * GRID))[tid];
        float s = (v.x + v.y) + (v.z + v.w);
        #pragma unroll
        for (int off = 32; off > 0; off >>= 1) s += __shfl_xor(s, off, 64);
        if ((tid & 63) == 0) wsum[tid >> 6] = s;
        __syncthreads();
        if (tid == 0) mg[blockIdx.x] = (wsum[0] + wsum[1]) + (wsum[2] + wsum[3]);
    } else if (blockIdx.x == NCH) {
        if (tid < NEXP) {
            const int e = tid;
            float A = 0.f, Cc = 0.f, P = 0.f, Q = 0.f;
            for (int i = 0; i < SEQL; ++i) {
                A  = fmaf(wq[e * SEQL + i], wk[e * SEQL + i], A);
                Cc = fmaf(bq[e * SEQL + i], wk[e * SEQL + i], Cc);
                P  = fmaf(wo[e * SEQL + i], wv[e * SEQL + i], P);
                Q  = fmaf(wo[e * SEQL + i], bv[e * SEQL + i], Q);
            }
            Q += bo[e];
            // fold log2(e) into A,C so phase C uses exp2f directly
            escal[e]      = A  * LOG2E;
            escal[22 + e] = Cc * LOG2E;
            escal[44 + e] = P;
            escal[66 + e] = Q;
        }
    }

    cg::this_grid().sync();

    // ---------------- Phase C: top-k + attention on the SAME 8 batches -------
    if (tid < 64) smg[tid] = (tid < NCH) ? mg[tid] : -FLT_MAX;
    if (tid >= 64 && tid < 64 + NEXP) {
        const int e = tid - 64;
        sA[e] = escal[e];       sC[e] = escal[22 + e];
        sP[e] = escal[44 + e];  sQ[e] = escal[66 + e];
    }
    __syncthreads();

    if (tid < 64) {   // wave-0 ballot top-22 + complement list
        const float v = smg[tid];
        int rank = 0;
        #pragma unroll
        for (int i = 0; i < NCH; ++i) {
            const float u = smg[i];
            rank += (u > v || (u == v && i < tid)) ? 1 : 0;
        }
        const bool seld = (tid < NCH) && (rank < NEXP);
        const unsigned long long m = __ballot(seld);
        if (seld) ssel[__popcll(m & ((1ull << tid) - 1ull))] = tid;
        const bool unsl = (tid < NCH) && (rank >= NEXP);
        const unsigned long long mu = __ballot(unsl);
        if (unsl) sunsel[__popcll(mu & ((1ull << tid) - 1ull))] = tid;
    }
    __syncthreads();

    // tasks: 8 batches x 22 experts x 21 l = 3696; thread owns a contiguous range
    {
        const int t0 = (tid * 3696) >> 8;
        const int t1 = ((tid + 1) * 3696) >> 8;
        int cur_be = -1;
        float xr[SEQL];
        float Ae = 0.f, Ce = 0.f, Pe = 0.f, Qe = 0.f, ge = 0.f;
        const float* xp = nullptr;
        int obase = 0;

        for (int tsk = t0; tsk < t1; ++tsk) {
            const int be = (tsk * 3121) >> 16;          // tsk/21, exact for tsk<13100
            if (be != cur_be) {
                cur_be = be;
                const int bi = (be * 2979) >> 16;       // be/22, exact for be<176
                const int e  = be - bi * NEXP;
                const int ch = ssel[e];
                xp = &xsh[bi * ROWLEN + ch * SEQL];
                #pragma unroll
                for (int m = 0; m < SEQL; ++m) xr[m] = xp[m];
                Ae = sA[e]; Ce = sC[e]; Pe = sP[e]; Qe = sQ[e];
                ge = gat[bi][ch];
                obase = (b_base + bi) * ROWLEN + ch * SEQL;
            }
            const int l = tsk - cur_be * SEQL;
            const float xl  = xp[l];                    // LDS read avoids dyn reg-index
            const float al2 = fmaf(Ae, xl, Ce);         // already log2e-scaled
            float den = 0.f, num = 0.f;
            #pragma unroll
            for (int m = 0; m < SEQL; ++m) {
                const float wgt = exp2f(al2 * xr[m]);
                den += wgt;
                num = fmaf(xr[m], wgt, num);
            }
            const float a = fmaf(Pe, __fdividef(num, den), Qe) * ge;
            out[obase + l]        = a * xl;             // G = A .* x
            out[GOFF + obase + l] = a;                  // A
        }
    }

    // zeros for the 23 unselected channels (8*23 = 184 rows)
    if (tid < 8 * NUN) {
        const int bi = tid / NUN;
        const int u  = tid - bi * NUN;
        const int ch = sunsel[u];
        const int ob = (b_base + bi) * ROWLEN + ch * SEQL;
        #pragma unroll
        for (int l = 0; l < SEQL; ++l) {
            out[ob + l]        = 0.f;
            out[GOFF + ob + l] = 0.f;
        }
    }
}

// =====================================================================
// Fallback path (proven 3-kernel structure) — used only if the fused
// kernel cannot be co-resident at grid=1024.
// =====================================================================
__global__ __launch_bounds__(256) void k1_gate(
    const float* __restrict__ x,
    const float* __restrict__ gc_w, const float* __restrict__ gc_b,
    const float* __restrict__ w1,   const float* __restrict__ b1,
    const float* __restrict__ w2,   const float* __restrict__ b2,
    float* __restrict__ gate_out,   float* __restrict__ partialsT)
{
    __shared__ float xsh[8 * ROWLEN];
    __shared__ float buf45a[4][45];
    __shared__ float buf45b[4][45];
    __shared__ float buf25a[4][25];
    __shared__ float buf25b[4][25];
    __shared__ float part[4][45];

    const int tid  = threadIdx.x;
    const int w    = tid >> 6;
    const int lane = tid & 63;
    const int b_base = blockIdx.x * 8;

    {
        const float4* x4 = (const float4*)(x + (size_t)b_base * ROWLEN);
        float4* xsh4 = (float4*)xsh;
        for (int q = tid; q < 1890; q += 256) xsh4[q] = x4[q];
    }
    __syncthreads();

    float acc = 0.f;
    for (int iter = 0; iter < 2; ++iter) {
        const int bb = w * 2 + iter;
        const int b  = b_base + bb;
        float g = 0.f;
        if (lane < NCH) {
            float xr[SEQL];
            const float* xp = &xsh[bb * ROWLEN + lane * SEQL];
            #pragma unroll
            for (int l = 0; l < SEQL; ++l) xr[l] = xp[l];
            float mx = -FLT_MAX, av = 0.f;
            for (int o = 0; o < SEQL; ++o) {
                float t = gc_b[o];
                #pragma unroll
                for (int l = 0; l < SEQL; ++l) t = fmaf(gc_w[o * SEQL + l], xr[l], t);
                mx = fmaxf(mx, t);
                av += t;
            }
            av *= (1.f / 21.f);
            buf45a[w][lane] = mx;
            buf45b[w][lane] = av;
        }
        __syncthreads();
        if (lane < 25) {
            float tm = b1[lane], ta = b1[lane];
            for (int i = 0; i < NCH; ++i) {
                const float wv_ = w1[lane * NCH + i];
                tm = fmaf(wv_, buf45a[w][i], tm);
                ta = fmaf(wv_, buf45b[w][i], ta);
            }
            buf25a[w][lane] = fast_tanh(tm);
            buf25b[w][lane] = fast_tanh(ta);
        }
        __syncthreads();
        if (lane < NCH) {
            float tm = b2[lane], ta = b2[lane];
            for (int j = 0; j < 25; ++j) {
                const float wv_ = w2[lane * 25 + j];
                tm = fmaf(wv_, buf25a[w][j], tm);
                ta = fmaf(wv_, buf25b[w][j], ta);
            }
            g = __expf(fast_tanh(tm) + fast_tanh(ta));
            buf45a[w][lane] = g;
        }
        __syncthreads();
        if (lane < NCH) {
            float s = 0.f;
            for (int i = 0; i < NCH; ++i) s += buf45a[w][i];
            const float gt = g / s;
            gate_out[(size_t)b * NCH + lane] = gt;
            acc += gt;
        }
        __syncthreads();
    }

    if (lane < NCH) part[w][lane] = acc;
    __syncthreads();
    if (tid < NCH)
        partialsT[tid * GRID + blockIdx.x] =
            part[0][tid] + part[1][tid] + part[2][tid] + part[3][tid];
}

__global__ __launch_bounds__(256) void k2_reduce(
    const float* __restrict__ partialsT,
    const float* __restrict__ wq, const float* __restrict__ bq,
    const float* __restrict__ wk, const float* __restrict__ bk,
    const float* __restrict__ wv, const float* __restrict__ bv,
    const float* __restrict__ wo, const float* __restrict__ bo,
    float* __restrict__ mg, float* __restrict__ escal)
{
    const int tid = threadIdx.x;
    const int c   = blockIdx.x;

    if (c < NCH) {
        __shared__ float wsum[4];
        const float4 v = ((const float4*)(partialsT + c * GRID))[tid];
        float s = (v.x + v.y) + (v.z + v.w);
        #pragma unroll
        for (int off = 32; off > 0; off >>= 1) s += __shfl_xor(s, off, 64);
        if ((tid & 63) == 0) wsum[tid >> 6] = s;
        __syncthreads();
        if (tid == 0) mg[c] = (wsum[0] + wsum[1]) + (wsum[2] + wsum[3]);
    } else {
        if (tid < NEXP) {
            const int e = tid;
            float A = 0.f, Cc = 0.f, P = 0.f, Q = 0.f;
            for (int i = 0; i < SEQL; ++i) {
                A  = fmaf(wq[e * SEQL + i], wk[e * SEQL + i], A);
                Cc = fmaf(bq[e * SEQL + i], wk[e * SEQL + i], Cc);
                P  = fmaf(wo[e * SEQL + i], wv[e * SEQL + i], P);
                Q  = fmaf(wo[e * SEQL + i], bv[e * SEQL + i], Q);
            }
            Q += bo[e];
            escal[e] = A; escal[22 + e] = Cc; escal[44 + e] = P; escal[66 + e] = Q;
        }
    }
}

__global__ __launch_bounds__(256) void k3_attn(
    const float* __restrict__ x, const float* __restrict__ gate,
    const float* __restrict__ mg, const float* __restrict__ escal,
    float* __restrict__ out)
{
    __shared__ float xsh[4 * ROWLEN];
    __shared__ float ash[4 * ROWLEN];
    __shared__ float smg[64];
    __shared__ float gat[4][NEXP];
    __shared__ float sA[NEXP], sC[NEXP], sP[NEXP], sQ[NEXP];
    __shared__ int   ssel[NEXP];

    const int tid = threadIdx.x;

    if (tid < 64) smg[tid] = (tid < NCH) ? mg[tid] : -FLT_MAX;
    if (tid >= 64 && tid < 64 + NEXP) {
        const int e = tid - 64;
        sA[e] = escal[e];       sC[e] = escal[22 + e];
        sP[e] = escal[44 + e];  sQ[e] = escal[66 + e];
    }

    const int b0 = blockIdx.x * 4;
    {
        const float4* x4 = (const float4*)x + (size_t)blockIdx.x * 945;
        float4* xsh4 = (float4*)xsh;
        float4* ash4 = (float4*)ash;
        const float4 z = make_float4(0.f, 0.f, 0.f, 0.f);
        for (int q = tid; q < 945; q += 256) {
            xsh4[q] = x4[q];
            ash4[q] = z;
        }
    }
    __syncthreads();

    if (tid < 64) {
        const float v = smg[tid];
        int rank = 0;
        #pragma unroll
        for (int i = 0; i < NCH; ++i) {
            const float u = smg[i];
            rank += (u > v || (u == v && i < tid)) ? 1 : 0;
        }
        const bool seld = (tid < NCH) && (rank < NEXP);
        const unsigned long long m = __ballot(seld);
        if (seld) {
            const int e = __popcll(m & ((1ull << tid) - 1ull));
            ssel[e] = tid;
        }
    }
    __syncthreads();

    if (tid < 4 * NEXP) {
        const int bi = tid / NEXP, e = tid - bi * NEXP;
        gat[bi][e] = gate[(size_t)(b0 + bi) * NCH + ssel[e]];
    }
    __syncthreads();

    {
        const int t0 = (tid * 1848) >> 8;
        const int t1 = ((tid + 1) * 1848) >> 8;
        int cur_be = -1;
        float xr[SEQL];
        float Ae = 0.f, Ce = 0.f, Pe = 0.f, Qe = 0.f, ge = 0.f;
        const float* xp = nullptr;
        float* ap = nullptr;

        for (int tsk = t0; tsk < t1; ++tsk) {
            const int be = (tsk * 3121) >> 16;
            if (be != cur_be) {
                cur_be = be;
                const int bi = (be * 2979) >> 16;
                const int e  = be - bi * NEXP;
                xp = &xsh[bi * ROWLEN + ssel[e] * SEQL];
                ap = &ash[bi * ROWLEN + ssel[e] * SEQL];
                #pragma unroll
                for (int m = 0; m < SEQL; ++m) xr[m] = xp[m];
                Ae = sA[e]; Ce = sC[e]; Pe = sP[e]; Qe = sQ[e];
                ge = gat[bi][e];
            }
            const int l = tsk - cur_be * SEQL;
            const float alpha = fmaf(Ae, xp[l], Ce);
            float den = 0.f, num = 0.f;
            #pragma unroll
            for (int m = 0; m < SEQL; ++m) {
                const float wgt = __expf(alpha * xr[m]);
                den += wgt;
                num = fmaf(xr[m], wgt, num);
            }
            ap[l] = fmaf(Pe, num / den, Qe) * ge;
        }
    }
    __syncthreads();

    {
        const float4* xsh4 = (const float4*)xsh;
        const float4* ash4 = (const float4*)ash;
        float4* g4 = (float4*)out + (size_t)blockIdx.x * 945;
        float4* a4 = (float4*)(out + (size_t)GOFF) + (size_t)blockIdx.x * 945;
        for (int q = tid; q < 945; q += 256) {
            const float4 a = ash4[q];
            const float4 xv = xsh4[q];
            g4[q] = make_float4(a.x * xv.x, a.y * xv.y, a.z * xv.z, a.w * xv.w);
            a4[q] = a;
        }
    }
}

extern "C" void kernel_launch(void* const* d_in, const int* in_sizes, int n_in,
                              void* d_out, int out_size, void* d_ws, size_t ws_size,
                              hipStream_t stream)
{
    const float* x    = (const float*)d_in[0];
    const float* gc_w = (const float*)d_in[1];
    const float* gc_b = (const float*)d_in[2];
    const float* w1   = (const float*)d_in[3];
    const float* b1   = (const float*)d_in[4];
    const float* w2   = (const float*)d_in[5];
    const float* b2   = (const float*)d_in[6];
    const float* wq   = (const float*)d_in[7];
    const float* bq   = (const float*)d_in[8];
    const float* wk   = (const float*)d_in[9];
    const float* bk   = (const float*)d_in[10];
    const float* wv   = (const float*)d_in[11];
    const float* bv   = (const float*)d_in[12];
    const float* wo   = (const float*)d_in[13];
    const float* bo   = (const float*)d_in[14];

    float* ws        = (float*)d_ws;
    float* partialsT = ws;                       // 45*1024 = 46080 floats
    float* mg        = ws + 46080;               // 45 floats (pad to 64)
    float* escal     = ws + 46144;               // 88 floats
    float* gateBuf   = ws + 46232;               // fallback only: BATCH*45
    float* outF      = (float*)d_out;

    // One-time co-residency check for the cooperative fused kernel.
    static int use_coop = -1;
    if (use_coop < 0) {
        int nb = 0;
        hipError_t e = hipOccupancyMaxActiveBlocksPerMultiprocessor(&nb, kfused, 256, 0);
        use_coop = (e == hipSuccess && nb >= 4) ? 1 : 0;   // need 4 blocks/CU * 256 CU = 1024
    }

    if (use_coop) {
        void* args[] = {
            (void*)&x,  (void*)&gc_w, (void*)&gc_b, (void*)&w1, (void*)&b1,
            (void*)&w2, (void*)&b2,   (void*)&wq,   (void*)&bq, (void*)&wk,
            (void*)&bk, (void*)&wv,   (void*)&bv,   (void*)&wo, (void*)&bo,
            (void*)&partialsT, (void*)&mg, (void*)&escal, (void*)&outF
        };
        hipError_t e = hipLaunchCooperativeKernel(reinterpret_cast<void*>(kfused),
                                                  dim3(GRID), dim3(256),
                                                  args, 0, stream);
        if (e == hipSuccess) return;
        use_coop = 0;   // fall through to proven path on any launch failure
    }

    k1_gate<<<dim3(GRID), dim3(256), 0, stream>>>(x, gc_w, gc_b, w1, b1, w2, b2,
                                                  gateBuf, partialsT);
    k2_reduce<<<dim3(46), dim3(256), 0, stream>>>(partialsT, wq, bq, wk, bk, wv, bv,
                                                  wo, bo, mg, escal);
    k3_attn<<<dim3(K3_BLOCKS), dim3(256), 0, stream>>>(x, gateBuf, mg, escal, outF);
}